// Round 1
// baseline (730.493 us; speedup 1.0000x reference)
//
#include <hip/hip_runtime.h>
#include <hip/hip_bf16.h>

// Problem constants
#define T_SEQ 2048
#define NBATCH 64
#define NIN 512
#define NH 3
#define NL 4

__device__ __forceinline__ float bperm(int byteaddr, float v) {
    return __int_as_float(__builtin_amdgcn_ds_bpermute(byteaddr, __float_as_int(v)));
}
__device__ __forceinline__ float frcp(float x) { return __builtin_amdgcn_rcpf(x); }
__device__ __forceinline__ float sigm(float x) { return frcp(1.0f + __expf(-x)); }
__device__ __forceinline__ float tanh_(float x) { return fmaf(-2.0f, frcp(1.0f + __expf(2.0f * x)), 1.0f); }

// ---------------------------------------------------------------------------
// Kernel 1: gx0[t][b][g] = sum_i x[t][b][i] * w_ih0[g][i] + b_ih0[g]
// M = T*B = 131072 rows of 512; 9 outputs per row.
// Block: 576 threads = 64 rows x 9 gate-rows. Grid: 2048 blocks.
// ---------------------------------------------------------------------------
__global__ __launch_bounds__(576) void gx0_kernel(
    const float* __restrict__ x,      // [M,512]
    const float* __restrict__ w,      // [9,512]
    const float* __restrict__ bias,   // [9]
    float* __restrict__ gx0)          // [M,9]
{
    __shared__ float wl[9 * 516];     // padded stride 516 to spread banks
    const int tid = threadIdx.x;
    for (int i = tid; i < 9 * 512; i += 576) {
        int g = i >> 9, c = i & 511;
        wl[g * 516 + c] = w[i];
    }
    __syncthreads();

    const int g    = tid % 9;
    const int rloc = tid / 9;
    const int row  = blockIdx.x * 64 + rloc;

    const float4* xr = reinterpret_cast<const float4*>(x + (size_t)row * NIN);
    const float4* wr = reinterpret_cast<const float4*>(&wl[g * 516]);

    float4 acc = make_float4(0.f, 0.f, 0.f, 0.f);
#pragma unroll 4
    for (int c = 0; c < NIN / 4; ++c) {
        float4 xv = xr[c];
        float4 wv = wr[c];
        acc.x = fmaf(xv.x, wv.x, acc.x);
        acc.y = fmaf(xv.y, wv.y, acc.y);
        acc.z = fmaf(xv.z, wv.z, acc.z);
        acc.w = fmaf(xv.w, wv.w, acc.w);
    }
    gx0[(size_t)row * 9 + g] = (acc.x + acc.y) + (acc.z + acc.w) + bias[g];
}

// ---------------------------------------------------------------------------
// Kernel 2: pipelined 4-layer GRU scan.
// 16 blocks x 64 threads (1 wave each, no LDS/barriers).
// Lane layout: lane = grp*16 + l*4 + j ; grp=batch-subgroup (4 batches/wave),
// l = layer 0..3, j = hidden index 0..2 (j==3 idle).
// Wave-step s: layer l processes t = s - l (software pipeline over layers).
// Cross-layer / cross-j data moves via ds_bpermute only.
// ---------------------------------------------------------------------------
__global__ __launch_bounds__(64) void gru_scan(
    const float* __restrict__ gx0,        // [T*64*9]  (includes b_ih0)
    const float* __restrict__ hxs,        // [4*64*3]
    const float* __restrict__ w_hh0,      // [9*3]
    const float* __restrict__ b_hh0,      // [9]
    const float* __restrict__ w_ih_rest,  // [3*9*3]
    const float* __restrict__ w_hh_rest,  // [3*9*3]
    const float* __restrict__ b_ih_rest,  // [3*9]
    const float* __restrict__ b_hh_rest,  // [3*9]
    float* __restrict__ out)              // [T*64*3 + 4*64*3]
{
    const int lane = threadIdx.x;
    const int grp  = lane >> 4;          // 0..3
    const int r    = lane & 15;
    const int l    = r >> 2;             // layer 0..3
    const int j    = r & 3;              // 0..3 (3 idle)
    const bool jok = (j < 3);
    const bool is0 = (l == 0);
    const bool is3 = (l == 3);
    const int  b   = blockIdx.x * 4 + grp;
    const int  row0 = jok ? j : 0;

    // ---- per-lane weights (rows j, 3+j, 6+j of the 9-row gate matrices) ----
    float wi[3][3], wh[3][3], bi[3], bh[3];
#pragma unroll
    for (int m = 0; m < 3; ++m) {
        const int row = m * 3 + row0;
        if (l == 0) {
            bi[m] = 0.f;
            bh[m] = b_hh0[row];
#pragma unroll
            for (int k = 0; k < 3; ++k) { wi[m][k] = 0.f; wh[m][k] = w_hh0[row * 3 + k]; }
        } else {
            bi[m] = b_ih_rest[(l - 1) * 9 + row];
            bh[m] = b_hh_rest[(l - 1) * 9 + row];
#pragma unroll
            for (int k = 0; k < 3; ++k) {
                wi[m][k] = w_ih_rest[((l - 1) * 9 + row) * 3 + k];
                wh[m][k] = w_hh_rest[((l - 1) * 9 + row) * 3 + k];
            }
        }
    }

    float h     = jok ? hxs[(l * NBATCH + b) * NH + j] : 0.f;
    float xprev = 0.f;

    // ---- bpermute byte addresses ----
    const int base = grp * 16;
    const int ah0 = (base + l * 4 + 0) * 4;
    const int ah1 = ah0 + 4;
    const int ah2 = ah0 + 8;
    int ax0, ax1, ax2;
    if (is0) { ax0 = lane * 4; ax1 = ax0; ax2 = ax0; }      // unused, self-read
    else     { ax0 = (base + (l - 1) * 4) * 4; ax1 = ax0 + 4; ax2 = ax0 + 8; }

    // ---- layer-0 gx prefetch (depth 2, two register buffers) ----
    const float* g0p = gx0 + (size_t)b * 9 + row0;          // + t*576 + {0,3,6}
    float ga0 = g0p[0],              ga1 = g0p[3],              ga2 = g0p[6];
    float gb0 = g0p[576 + 0],        gb1 = g0p[576 + 3],        gb2 = g0p[576 + 6];

#define STEP(S, B0, B1, B2)                                                          \
    do {                                                                             \
        const int t = (S) - l;                                                       \
        const bool act = (t >= 0) && (t < T_SEQ);                                    \
        float xv0 = bperm(ax0, xprev);                                               \
        float xv1 = bperm(ax1, xprev);                                               \
        float xv2 = bperm(ax2, xprev);                                               \
        float hv0 = bperm(ah0, h);                                                   \
        float hv1 = bperm(ah1, h);                                                   \
        float hv2 = bperm(ah2, h);                                                   \
        float c0 = is0 ? B0 : bi[0];                                                 \
        float c1 = is0 ? B1 : bi[1];                                                 \
        float c2 = is0 ? B2 : bi[2];                                                 \
        if (is0) {                                                                   \
            int tt = t + 2; tt = (tt > T_SEQ - 1) ? (T_SEQ - 1) : tt;                \
            B0 = g0p[(size_t)tt * 576];                                              \
            B1 = g0p[(size_t)tt * 576 + 3];                                          \
            B2 = g0p[(size_t)tt * 576 + 6];                                          \
        }                                                                            \
        float gxr = fmaf(wi[0][0], xv0, fmaf(wi[0][1], xv1, fmaf(wi[0][2], xv2, c0)));\
        float gxz = fmaf(wi[1][0], xv0, fmaf(wi[1][1], xv1, fmaf(wi[1][2], xv2, c1)));\
        float gxn = fmaf(wi[2][0], xv0, fmaf(wi[2][1], xv1, fmaf(wi[2][2], xv2, c2)));\
        float ghr = fmaf(wh[0][0], hv0, fmaf(wh[0][1], hv1, fmaf(wh[0][2], hv2, bh[0])));\
        float ghz = fmaf(wh[1][0], hv0, fmaf(wh[1][1], hv1, fmaf(wh[1][2], hv2, bh[1])));\
        float ghn = fmaf(wh[2][0], hv0, fmaf(wh[2][1], hv1, fmaf(wh[2][2], hv2, bh[2])));\
        float rr = sigm(gxr + ghr);                                                  \
        float zz = sigm(gxz + ghz);                                                  \
        float nn = tanh_(fmaf(rr, ghn, gxn));                                        \
        float hn = fmaf(zz, h - nn, nn);                                             \
        if (act) {                                                                   \
            h = hn;                                                                  \
            xprev = hn;                                                              \
            if (is3 && jok) out[(size_t)t * 192 + b * 3 + j] = hn;                   \
            if ((t == T_SEQ - 1) && jok)                                             \
                out[(size_t)T_SEQ * 192 + (l * NBATCH + b) * 3 + j] = hn;            \
        }                                                                            \
    } while (0)

    // 2051 wave-steps needed (s = 0 .. 2050); run 2052 (even) for unroll-2.
    for (int s = 0; s < T_SEQ + 4; s += 2) {
        STEP(s,     ga0, ga1, ga2);
        STEP(s + 1, gb0, gb1, gb2);
    }
#undef STEP
}

// ---------------------------------------------------------------------------
extern "C" void kernel_launch(void* const* d_in, const int* in_sizes, int n_in,
                              void* d_out, int out_size, void* d_ws, size_t ws_size,
                              hipStream_t stream) {
    const float* x         = (const float*)d_in[0];
    const float* hxs       = (const float*)d_in[1];
    const float* w_ih0     = (const float*)d_in[2];
    const float* w_hh0     = (const float*)d_in[3];
    const float* b_ih0     = (const float*)d_in[4];
    const float* b_hh0     = (const float*)d_in[5];
    const float* w_ih_rest = (const float*)d_in[6];
    const float* w_hh_rest = (const float*)d_in[7];
    const float* b_ih_rest = (const float*)d_in[8];
    const float* b_hh_rest = (const float*)d_in[9];
    float* out = (float*)d_out;
    float* gx0 = (float*)d_ws;   // needs T*64*9*4 = 4.72 MB

    hipLaunchKernelGGL(gx0_kernel, dim3((T_SEQ * NBATCH) / 64), dim3(576), 0, stream,
                       x, w_ih0, b_ih0, gx0);
    hipLaunchKernelGGL(gru_scan, dim3(16), dim3(64), 0, stream,
                       gx0, hxs, w_hh0, b_hh0, w_ih_rest, w_hh_rest,
                       b_ih_rest, b_hh_rest, out);
}

// Round 2
// 387.400 us; speedup vs baseline: 1.8856x; 1.8856x over previous
//
#include <hip/hip_runtime.h>
#include <hip/hip_bf16.h>

// Problem constants
#define T_SEQ 2048
#define NBATCH 64
#define NIN 512
#define NH 3
#define NL 4

// ---------------- cross-lane helpers ----------------
template<int CTRL>
__device__ __forceinline__ float dppmov(float v) {
    // old=0, row_mask=0xF, bank_mask=0xF, bound_ctrl=true (invalid lanes -> 0)
    return __int_as_float(__builtin_amdgcn_update_dpp(
        0, __float_as_int(v), CTRL, 0xF, 0xF, true));
}
template<int CTRL>
__device__ __forceinline__ float dppadd(float v) { return v + dppmov<CTRL>(v); }

__device__ __forceinline__ float swzadd16(float v) {   // lane ^= 16 (within 32)
    return v + __int_as_float(__builtin_amdgcn_ds_swizzle(__float_as_int(v), 0x401F));
}

__device__ __forceinline__ float frcp(float x) { return __builtin_amdgcn_rcpf(x); }
__device__ __forceinline__ float sigm(float x) { return frcp(1.0f + __expf(-x)); }
__device__ __forceinline__ float tanh_(float x) { return fmaf(-2.0f, frcp(1.0f + __expf(2.0f * x)), 1.0f); }

// ---------------------------------------------------------------------------
// Kernel 1: gx0[row][g] = dot(x[row], w[g]) + b[g], row in [0,131072), g in [0,9)
// One row per 64-lane wave-iteration. w slice (72 f32) in registers. x reads
// perfectly coalesced (lane*16B). DPP/swizzle tree reduction, no LDS.
// Grid: 2048 blocks x 256 threads = 8192 waves x 16 rows.
// ---------------------------------------------------------------------------
__global__ __launch_bounds__(256) void gx0_kernel(
    const float* __restrict__ x,      // [131072,512]
    const float* __restrict__ w,      // [9,512]
    const float* __restrict__ bias,   // [9]
    float* __restrict__ gx0)          // [131072,9]
{
    const int lane = threadIdx.x & 63;
    const int gw   = (blockIdx.x * 256 + threadIdx.x) >> 6;   // 0..8191

    // per-lane w slice: columns [lane*4, lane*4+4) and [256+lane*4, ...)
    float4 wA[9], wB[9];
#pragma unroll
    for (int g = 0; g < 9; ++g) {
        wA[g] = *(const float4*)&w[g * 512 + lane * 4];
        wB[g] = *(const float4*)&w[g * 512 + 256 + lane * 4];
    }
    const float bval = (lane < 9) ? bias[lane] : 0.f;

    size_t row0 = (size_t)gw * 16;
    const float4* xp = (const float4*)(x + row0 * NIN);   // row stride = 128 float4

    float4 xa = xp[lane];
    float4 xb = xp[64 + lane];

#pragma unroll 1
    for (int i = 0; i < 16; ++i) {
        float4 na = xa, nb = xb;
        if (i < 15) {                       // prefetch next row (coalesced)
            na = xp[(i + 1) * 128 + lane];
            nb = xp[(i + 1) * 128 + 64 + lane];
        }
        float r[9];
#pragma unroll
        for (int g = 0; g < 9; ++g) {
            float s = xa.x * wA[g].x;
            s = fmaf(xa.y, wA[g].y, s);
            s = fmaf(xa.z, wA[g].z, s);
            s = fmaf(xa.w, wA[g].w, s);
            s = fmaf(xb.x, wB[g].x, s);
            s = fmaf(xb.y, wB[g].y, s);
            s = fmaf(xb.z, wB[g].z, s);
            s = fmaf(xb.w, wB[g].w, s);
            // wave-wide sum: quads (xor1,xor2), row-of-16 (ror4,ror8),
            // cross-row (swizzle xor16), cross-half (shfl_xor 32)
            s = dppadd<0xB1>(s);            // quad_perm [1,0,3,2]
            s = dppadd<0x4E>(s);            // quad_perm [2,3,0,1]
            s = dppadd<0x124>(s);           // row_ror:4
            s = dppadd<0x128>(s);           // row_ror:8
            s = swzadd16(s);
            s += __shfl_xor(s, 32, 64);
            r[g] = s;
        }
        float o = r[0];
#pragma unroll
        for (int g = 1; g < 9; ++g) o = (lane == g) ? r[g] : o;
        if (lane < 9) gx0[(row0 + i) * 9 + lane] = o + bval;
        xa = na; xb = nb;
    }
}

// ---------------------------------------------------------------------------
// Kernel 2: pipelined 4-layer GRU scan.
// 16 blocks x 64 threads (1 wave each). Lane = grp*16 + l*4 + j.
// All cross-lane comm via DPP (quad_perm broadcast + row_shr:4).
// Layer-0 gx: depth-8 rotating register prefetch (hides ~1000cy latency).
// ---------------------------------------------------------------------------
__global__ __launch_bounds__(64) void gru_scan(
    const float* __restrict__ gx0,        // [T*64*9] (includes b_ih0)
    const float* __restrict__ hxs,        // [4*64*3]
    const float* __restrict__ w_hh0,      // [9*3]
    const float* __restrict__ b_hh0,      // [9]
    const float* __restrict__ w_ih_rest,  // [3*9*3]
    const float* __restrict__ w_hh_rest,  // [3*9*3]
    const float* __restrict__ b_ih_rest,  // [3*9]
    const float* __restrict__ b_hh_rest,  // [3*9]
    float* __restrict__ out)              // [T*64*3 + 4*64*3]
{
    const int lane = threadIdx.x;
    const int grp  = lane >> 4;
    const int r    = lane & 15;
    const int l    = r >> 2;             // layer 0..3
    const int j    = r & 3;              // 0..3 (3 idle)
    const bool jok = (j < 3);
    const bool is0 = (l == 0);
    const bool is3 = (l == 3);
    const int  b   = blockIdx.x * 4 + grp;
    const int  row0 = jok ? j : 0;

    float wi[3][3], wh[3][3], bi[3], bh[3];
#pragma unroll
    for (int m = 0; m < 3; ++m) {
        const int row = m * 3 + row0;
        if (l == 0) {
            bi[m] = 0.f;
            bh[m] = b_hh0[row];
#pragma unroll
            for (int k = 0; k < 3; ++k) { wi[m][k] = 0.f; wh[m][k] = w_hh0[row * 3 + k]; }
        } else {
            bi[m] = b_ih_rest[(l - 1) * 9 + row];
            bh[m] = b_hh_rest[(l - 1) * 9 + row];
#pragma unroll
            for (int k = 0; k < 3; ++k) {
                wi[m][k] = w_ih_rest[((l - 1) * 9 + row) * 3 + k];
                wh[m][k] = w_hh_rest[((l - 1) * 9 + row) * 3 + k];
            }
        }
    }

    float h = jok ? hxs[(l * NBATCH + b) * NH + j] : 0.f;

    // layer-0 gx pointer: independent of l (all lanes mirror their layer-0
    // counterpart -> loads coalesce onto the same cachelines, no divergence)
    const float* g0p = gx0 + (size_t)b * 9 + row0;   // + t*576 + {0,3,6}

    float gp[8][3];
#pragma unroll
    for (int p = 0; p < 8; ++p) {
        gp[p][0] = g0p[(size_t)p * 576];
        gp[p][1] = g0p[(size_t)p * 576 + 3];
        gp[p][2] = g0p[(size_t)p * 576 + 6];
    }

    // 2051 wave-steps needed; run 2056 = 257*8.
#pragma unroll 1
    for (int s0 = 0; s0 < T_SEQ + 8; s0 += 8) {
#pragma unroll
        for (int p = 0; p < 8; ++p) {
            const int s = s0 + p;
            const int t = s - l;
            // own-layer h broadcast within quad, prev-layer via row_shr:4
            float hv0 = dppmov<0x00>(h);
            float hv1 = dppmov<0x55>(h);
            float hv2 = dppmov<0xAA>(h);
            float xv0 = dppmov<0x114>(hv0);   // row_shr:4 -> layer l-1 (0 for l==0)
            float xv1 = dppmov<0x114>(hv1);
            float xv2 = dppmov<0x114>(hv2);
            float c0 = is0 ? gp[p][0] : bi[0];
            float c1 = is0 ? gp[p][1] : bi[1];
            float c2 = is0 ? gp[p][2] : bi[2];
            {   // reload this slot for step s+8 (clamped; dup loads hit L1)
                int tt = s + 8; tt = tt > T_SEQ - 1 ? T_SEQ - 1 : tt;
                gp[p][0] = g0p[(size_t)tt * 576];
                gp[p][1] = g0p[(size_t)tt * 576 + 3];
                gp[p][2] = g0p[(size_t)tt * 576 + 6];
            }
            float gxr = fmaf(wi[0][0], xv0, fmaf(wi[0][1], xv1, fmaf(wi[0][2], xv2, c0)));
            float gxz = fmaf(wi[1][0], xv0, fmaf(wi[1][1], xv1, fmaf(wi[1][2], xv2, c1)));
            float gxn = fmaf(wi[2][0], xv0, fmaf(wi[2][1], xv1, fmaf(wi[2][2], xv2, c2)));
            float ghr = fmaf(wh[0][0], hv0, fmaf(wh[0][1], hv1, fmaf(wh[0][2], hv2, bh[0])));
            float ghz = fmaf(wh[1][0], hv0, fmaf(wh[1][1], hv1, fmaf(wh[1][2], hv2, bh[1])));
            float ghn = fmaf(wh[2][0], hv0, fmaf(wh[2][1], hv1, fmaf(wh[2][2], hv2, bh[2])));
            float rr = sigm(gxr + ghr);
            float zz = sigm(gxz + ghz);
            float nn = tanh_(fmaf(rr, ghn, gxn));
            float hn = fmaf(zz, h - nn, nn);
            const bool act = (t >= 0) && (t < T_SEQ);
            h = act ? hn : h;
            if (act && is3 && jok) out[(size_t)t * 192 + b * 3 + j] = hn;
            if ((t == T_SEQ - 1) && jok)
                out[(size_t)T_SEQ * 192 + (l * NBATCH + b) * 3 + j] = hn;
        }
    }
}

// ---------------------------------------------------------------------------
extern "C" void kernel_launch(void* const* d_in, const int* in_sizes, int n_in,
                              void* d_out, int out_size, void* d_ws, size_t ws_size,
                              hipStream_t stream) {
    const float* x         = (const float*)d_in[0];
    const float* hxs       = (const float*)d_in[1];
    const float* w_ih0     = (const float*)d_in[2];
    const float* w_hh0     = (const float*)d_in[3];
    const float* b_ih0     = (const float*)d_in[4];
    const float* b_hh0     = (const float*)d_in[5];
    const float* w_ih_rest = (const float*)d_in[6];
    const float* w_hh_rest = (const float*)d_in[7];
    const float* b_ih_rest = (const float*)d_in[8];
    const float* b_hh_rest = (const float*)d_in[9];
    float* out = (float*)d_out;
    float* gx0 = (float*)d_ws;   // T*64*9*4 = 4.72 MB

    hipLaunchKernelGGL(gx0_kernel, dim3(2048), dim3(256), 0, stream,
                       x, w_ih0, b_ih0, gx0);
    hipLaunchKernelGGL(gru_scan, dim3(16), dim3(64), 0, stream,
                       gx0, hxs, w_hh0, b_hh0, w_ih_rest, w_hh_rest,
                       b_ih_rest, b_hh_rest, out);
}